// Round 15
// baseline (904.479 us; speedup 1.0000x reference)
//
#include <hip/hip_runtime.h>
#include <hip/hip_bf16.h>

#define DIN 8192
#define HH 4096
#define BLT 2048   // total tokens (2*1024)
#define LSEQ 1024
#define CL 64      // scan chunk length
#define NCG 32     // total chunks (16 per batch)

typedef unsigned short u16;
typedef __bf16 bf16x8 __attribute__((ext_vector_type(8)));
typedef float f32x4v __attribute__((ext_vector_type(4)));

__device__ __forceinline__ u16 f2b(float f) {
  unsigned u = __float_as_uint(f);
  u += 0x7fff + ((u >> 16) & 1);
  return (u16)(u >> 16);
}
__device__ __forceinline__ float b2f(u16 h) {
  return __uint_as_float(((unsigned)h) << 16);
}

__device__ __forceinline__ void gl_lds16(const u16* g, u16* l) {
  __builtin_amdgcn_global_load_lds(
      (const __attribute__((address_space(1))) void*)g,
      (__attribute__((address_space(3))) void*)l, 16, 0, 0);
}

__device__ __forceinline__ int bsw(int r) { return (r & 3) ^ ((r >> 2) & 3); }

// ---- merged input converts: W_in (67.1M) + hs (8.4M), f32 -> bf16 ----
__global__ void cvt_in_kernel(const float* __restrict__ Win, u16* __restrict__ Winb,
                              const float* __restrict__ hs, u16* __restrict__ hsb) {
  const long stride = (long)gridDim.x * blockDim.x * 4;
  const long base = ((long)blockIdx.x * blockDim.x + threadIdx.x) * 4;
  for (long i = base; i < 67108864L; i += stride) {
    f32x4v v = *(const f32x4v*)(Win + i);
    ushort4 o;
    o.x = f2b(v[0]); o.y = f2b(v[1]); o.z = f2b(v[2]); o.w = f2b(v[3]);
    *(ushort4*)(Winb + i) = o;
  }
  for (long i = base; i < 8388608L; i += stride) {
    f32x4v v = *(const f32x4v*)(hs + i);
    ushort4 o;
    o.x = f2b(v[0]); o.y = f2b(v[1]); o.z = f2b(v[2]); o.w = f2b(v[3]);
    *(ushort4*)(hsb + i) = o;
  }
}

// ---- merged weight converts: W_out, W_dt, W_x (pad 288->512 rows) ----
__global__ void cvt_weights_kernel(
    const float* __restrict__ Wout, u16* __restrict__ Woutb,
    const float* __restrict__ Wdt, u16* __restrict__ Wdtb,
    const float* __restrict__ Wx, u16* __restrict__ Wxb)
{
  const long stride = (long)gridDim.x * blockDim.x * 4;
  const long base = ((long)blockIdx.x * blockDim.x + threadIdx.x) * 4;
  for (long i = base; i < 33554432L; i += stride) {
    f32x4v v = *(const f32x4v*)(Wout + i);
    ushort4 o;
    o.x = f2b(v[0]); o.y = f2b(v[1]); o.z = f2b(v[2]); o.w = f2b(v[3]);
    *(ushort4*)(Woutb + i) = o;
  }
  for (long i = base; i < 2097152L; i += stride) {
    f32x4v v = *(const f32x4v*)(Wdt + i);
    ushort4 o;
    o.x = f2b(v[0]); o.y = f2b(v[1]); o.z = f2b(v[2]); o.w = f2b(v[3]);
    *(ushort4*)(Wdtb + i) = o;
  }
  for (long i = base; i < (long)512 * DIN; i += stride) {
    ushort4 o;
    if (i < (long)288 * DIN) {
      f32x4v v = *(const f32x4v*)(Wx + i);
      o.x = f2b(v[0]); o.y = f2b(v[1]); o.z = f2b(v[2]); o.w = f2b(v[3]);
    } else {
      o.x = 0; o.y = 0; o.z = 0; o.w = 0;
    }
    *(ushort4*)(Wxb + i) = o;
  }
}

// ------- 256x256 8-wave GEMM, phase-split (reads-before-barrier), 3-stage -------
// Tile order: m-fastest within XCD chunk (B column-panel L2-resident, B streamed
// from HBM once; A panel L3-resident).
// MODE 0: f32 out [z][M][N] partials (cols < nlim only).  MODE 1: bf16 out [M][N].
// MODE 2: f32 out [M][N] with fused softplus(acc + bias[row]) (dt path, A=W_dt).
template<int MODE>
__global__ __launch_bounds__(512, 2) void gemm256(
    const u16* __restrict__ A, const u16* __restrict__ B, void* __restrict__ Cp,
    int M, int N, int Kfull, int Ksub, const float* __restrict__ bias = nullptr,
    int nlim = 1 << 30)
{
  __shared__ __align__(16) u16 lds[3][2][8192];  // [buf][A=0/B=1][256 rows][32 k]
  const int tid = threadIdx.x;
  const int lane = tid & 63;
  const int wid = tid >> 6;
  const int wm = wid >> 2;
  const int wn = wid & 3;
  const int fr = lane & 15;
  const int fq = lane >> 4;
  const int fs = fq ^ bsw(fr);

  // XCD-aware swizzle over grid.x; m varies fastest
  const int nbm = M >> 8;
  const int cpx = gridDim.x >> 3;
  const int bid = blockIdx.x;
  const int swz = (bid & 7) * cpx + (bid >> 3);
  const long m0 = (long)(swz % nbm) << 8;
  const long n0 = (long)(swz / nbm) << 8;
  const long kbase = (long)blockIdx.y * Ksub;

  const int srow = tid >> 2;
  const int sseg = (tid & 3) ^ bsw(srow);
  const u16* ag0 = A + (m0 + srow) * (long)Kfull + kbase + sseg * 8;
  const u16* ag1 = ag0 + 128 * (long)Kfull;
  const u16* bg0 = B + (n0 + srow) * (long)Kfull + kbase + sseg * 8;
  const u16* bg1 = bg0 + 128 * (long)Kfull;

  auto stageA = [&](int c, int koff) {          // first halves of A and B tiles
    gl_lds16(ag0 + koff, &lds[c][0][tid * 8]);
    gl_lds16(bg0 + koff, &lds[c][1][tid * 8]);
  };
  auto stageB = [&](int c, int koff) {          // second halves
    gl_lds16(ag1 + koff, &lds[c][0][4096 + tid * 8]);
    gl_lds16(bg1 + koff, &lds[c][1][4096 + tid * 8]);
  };

  const int NT = Ksub >> 5;
  stageA(0, 0); stageB(0, 0);
  stageA(1, 32); stageB(1, 32);
  asm volatile("s_waitcnt vmcnt(4)" ::: "memory");  // tile0 landed
  __builtin_amdgcn_s_barrier();

  f32x4v acc[8][4];
#pragma unroll
  for (int i = 0; i < 8; ++i)
#pragma unroll
    for (int j = 0; j < 4; ++j) acc[i][j] = (f32x4v){0.f, 0.f, 0.f, 0.f};

  const int aoff = (wm * 128 + fr) * 32 + fs * 8;
  const int boff = (wn * 64 + fr) * 32 + fs * 8;
  bf16x8 af[4], bfg[4], al[4];

  int c = 0, cs = 2;
  for (int t = 0; t < NT; ++t) {
    const u16* Asl = &lds[c][0][0];
    const u16* Bsl = &lds[c][1][0];
    const bool pf = (t + 2 < NT);
    // ---- phase A: issue reads (af,bfg), issue half of stage(t+2), barrier ----
#pragma unroll
    for (int mi = 0; mi < 4; ++mi) af[mi] = *(const bf16x8*)(Asl + aoff + mi * 512);
#pragma unroll
    for (int ni = 0; ni < 4; ++ni) bfg[ni] = *(const bf16x8*)(Bsl + boff + ni * 512);
    if (pf) stageA(cs, (t + 2) * 32);
    __builtin_amdgcn_s_barrier();                       // ds latency hides here
    asm volatile("s_waitcnt lgkmcnt(0)" ::: "memory");
    __builtin_amdgcn_sched_barrier(0);
    __builtin_amdgcn_s_setprio(1);
#pragma unroll
    for (int mi = 0; mi < 4; ++mi)
#pragma unroll
      for (int ni = 0; ni < 4; ++ni)
        acc[mi][ni] = __builtin_amdgcn_mfma_f32_16x16x32_bf16(af[mi], bfg[ni], acc[mi][ni], 0, 0, 0);
    __builtin_amdgcn_s_setprio(0);
    // ---- phase B: issue reads (al), other half of stage(t+2), barrier ----
#pragma unroll
    for (int mi = 0; mi < 4; ++mi) al[mi] = *(const bf16x8*)(Asl + aoff + 2048 + mi * 512);
    if (pf) stageB(cs, (t + 2) * 32);
    __builtin_amdgcn_s_barrier();
    asm volatile("s_waitcnt lgkmcnt(0)" ::: "memory");
    __builtin_amdgcn_sched_barrier(0);
    __builtin_amdgcn_s_setprio(1);
#pragma unroll
    for (int mi = 0; mi < 4; ++mi)
#pragma unroll
      for (int ni = 0; ni < 4; ++ni)
        acc[mi + 4][ni] = __builtin_amdgcn_mfma_f32_16x16x32_bf16(al[mi], bfg[ni], acc[mi + 4][ni], 0, 0, 0);
    __builtin_amdgcn_s_setprio(0);
    if (pf) {
      asm volatile("s_waitcnt vmcnt(4)" ::: "memory");  // t+1 landed; t+2 in flight
    } else {
      asm volatile("s_waitcnt vmcnt(0)" ::: "memory");  // drain tail
    }
    __builtin_amdgcn_s_barrier();   // all waves: buf c reads done + t+1 visible
    c = (c == 2) ? 0 : c + 1;
    cs = (cs == 2) ? 0 : cs + 1;
  }

  float* Cf = (float*)Cp + (size_t)blockIdx.y * M * N;
#pragma unroll
  for (int mi = 0; mi < 8; ++mi) {
#pragma unroll
    for (int ni = 0; ni < 4; ++ni) {
      const long col = n0 + wn * 64 + ni * 16 + fr;
      const long rbase = m0 + wm * 128 + mi * 16 + fq * 4;
#pragma unroll
      for (int r = 0; r < 4; ++r) {
        if constexpr (MODE == 1) {
          ((u16*)Cp)[(rbase + r) * N + col] = f2b(acc[mi][ni][r]);
        } else if constexpr (MODE == 0) {
          if (col < nlim) Cf[(rbase + r) * N + col] = acc[mi][ni][r];
        } else {
          const float z = acc[mi][ni][r] + bias[rbase + r];
          ((float*)Cp)[(rbase + r) * N + col] = (z > 20.f) ? z : log1pf(__expf(z));
        }
      }
    }
  }
}

// ---- 256x128-tile 8-wave GEMM (full K, f32 direct out) — for out = yg @ W_out^T ----
// 8 waves as 4(m) x 2(n), per-wave 64x64 output. LDS 3 x (16KB A + 8KB B) = 72KB.
// m-fastest tile order.
__global__ __launch_bounds__(512, 2) void gemm256n128(
    const u16* __restrict__ A, const u16* __restrict__ B, float* __restrict__ Cp,
    int M, int N, int K)
{
  __shared__ __align__(16) u16 lds[3][12288];   // [buf][A: 0..8191 | B: 8192..12287]
  const int tid = threadIdx.x;
  const int lane = tid & 63;
  const int wid = tid >> 6;
  const int wm = wid >> 1;    // 0..3
  const int wn = wid & 1;     // 0..1
  const int fr = lane & 15;
  const int fq = lane >> 4;
  const int fs = fq ^ bsw(fr);

  // XCD-aware swizzle; m varies fastest
  const int nbm = M >> 8;
  const int cpx = gridDim.x >> 3;
  const int bid = blockIdx.x;
  const int swz = (bid & 7) * cpx + (bid >> 3);
  const long m0 = (long)(swz % nbm) << 8;
  const long n0 = (long)(swz / nbm) << 7;

  const int srow = tid >> 2;                    // 0..127
  const int sseg = (tid & 3) ^ bsw(srow);
  const u16* ag0 = A + (m0 + srow) * (long)K + sseg * 8;
  const u16* ag1 = ag0 + 128 * (long)K;
  const u16* bg0 = B + (n0 + srow) * (long)K + sseg * 8;

  auto stage = [&](int c, int koff) {
    gl_lds16(ag0 + koff, &lds[c][tid * 8]);
    gl_lds16(ag1 + koff, &lds[c][4096 + tid * 8]);
    gl_lds16(bg0 + koff, &lds[c][8192 + tid * 8]);
  };

  const int NT = K >> 5;
  stage(0, 0);
  stage(1, 32);
  asm volatile("s_waitcnt vmcnt(3)" ::: "memory");   // tile0's 3 loads landed
  __builtin_amdgcn_s_barrier();

  f32x4v acc[4][4];
#pragma unroll
  for (int i = 0; i < 4; ++i)
#pragma unroll
    for (int j = 0; j < 4; ++j) acc[i][j] = (f32x4v){0.f, 0.f, 0.f, 0.f};

  const int aoff = (wm * 64 + fr) * 32 + fs * 8;     // + mi*512
  const int boff = 8192 + (wn * 64 + fr) * 32 + fs * 8;  // + ni*512
  bf16x8 af[4], bfg[4];

  int c = 0, cs = 2;
  for (int t = 0; t < NT; ++t) {
    const u16* L = &lds[c][0];
    const bool pf = (t + 2 < NT);
#pragma unroll
    for (int mi = 0; mi < 4; ++mi) af[mi] = *(const bf16x8*)(L + aoff + mi * 512);
#pragma unroll
    for (int ni = 0; ni < 4; ++ni) bfg[ni] = *(const bf16x8*)(L + boff + ni * 512);
    if (pf) stage(cs, (t + 2) * 32);
    __builtin_amdgcn_s_barrier();
    asm volatile("s_waitcnt lgkmcnt(0)" ::: "memory");
    __builtin_amdgcn_sched_barrier(0);
    __builtin_amdgcn_s_setprio(1);
#pragma unroll
    for (int mi = 0; mi < 4; ++mi)
#pragma unroll
      for (int ni = 0; ni < 4; ++ni)
        acc[mi][ni] = __builtin_amdgcn_mfma_f32_16x16x32_bf16(af[mi], bfg[ni], acc[mi][ni], 0, 0, 0);
    __builtin_amdgcn_s_setprio(0);
    if (pf) {
      asm volatile("s_waitcnt vmcnt(3)" ::: "memory");  // t+1 landed; t+2 in flight
    } else {
      asm volatile("s_waitcnt vmcnt(0)" ::: "memory");  // drain tail
    }
    __builtin_amdgcn_s_barrier();   // reads of buf c done + t+1 visible
    c = (c == 2) ? 0 : c + 1;
    cs = (cs == 2) ? 0 : cs + 1;
  }

#pragma unroll
  for (int mi = 0; mi < 4; ++mi) {
#pragma unroll
    for (int ni = 0; ni < 4; ++ni) {
      const long col = n0 + wn * 64 + ni * 16 + fr;
      const long rbase = m0 + wm * 64 + mi * 16 + fq * 4;
#pragma unroll
      for (int r = 0; r < 4; ++r)
        Cp[(rbase + r) * N + col] = acc[mi][ni][r];
    }
  }
}

// ---- causal conv (K=4) + SiLU, 64x64 tile; writes x AND x^T (LDS transpose) ----
__global__ __launch_bounds__(256) void conv_silu_tr_kernel(
    const u16* __restrict__ proj, const float* __restrict__ conv_w,
    const float* __restrict__ conv_b, u16* __restrict__ xb, u16* __restrict__ xT)
{
  __shared__ u16 xt[64][68];   // +4 pad keeps 8B align, breaks bank conflicts
  const int t = threadIdx.x;
  const int tr = t >> 4;          // 0..15 token row base
  const int dqi = t & 15;         // d offset = dqi*4
  const long tok0 = (long)blockIdx.x * 64;
  const int d0 = blockIdx.y * 64;
  const int d = d0 + dqi * 4;
  f32x4v cb = *(const f32x4v*)(conv_b + d);
  f32x4v w0 = *(const f32x4v*)(conv_w + (size_t)(d + 0) * 4);
  f32x4v w1 = *(const f32x4v*)(conv_w + (size_t)(d + 1) * 4);
  f32x4v w2 = *(const f32x4v*)(conv_w + (size_t)(d + 2) * 4);
  f32x4v w3 = *(const f32x4v*)(conv_w + (size_t)(d + 3) * 4);
#pragma unroll
  for (int tt = 0; tt < 4; ++tt) {
    const long tok = tok0 + tr + tt * 16;
    const int l = (int)(tok & (LSEQ - 1));
    float a0 = cb[0], a1 = cb[1], a2 = cb[2], a3 = cb[3];
#pragma unroll
    for (int j = 0; j < 4; ++j) {
      const int lj = l - 3 + j;
      if (lj >= 0) {
        ushort4 xv = *(const ushort4*)(proj + (tok - 3 + j) * 16384 + d);
        a0 = fmaf(w0[j], b2f(xv.x), a0);
        a1 = fmaf(w1[j], b2f(xv.y), a1);
        a2 = fmaf(w2[j], b2f(xv.z), a2);
        a3 = fmaf(w3[j], b2f(xv.w), a3);
      }
    }
    ushort4 o;
    o.x = f2b(a0 / (1.f + __expf(-a0)));
    o.y = f2b(a1 / (1.f + __expf(-a1)));
    o.z = f2b(a2 / (1.f + __expf(-a2)));
    o.w = f2b(a3 / (1.f + __expf(-a3)));
    *(ushort4*)(xb + tok * DIN + d) = o;
    *(ushort4*)(&xt[tr + tt * 16][dqi * 4]) = o;
  }
  __syncthreads();
  // transpose out: thread t -> d_local = t>>2, token quarter = t&3
  const int dl = t >> 2;
  const int tq = t & 3;
  u16 buf[16];
#pragma unroll
  for (int i = 0; i < 16; ++i) buf[i] = xt[tq * 16 + i][dl];
  u16* dst = xT + (size_t)(d0 + dl) * BLT + tok0 + tq * 16;
  *(ushort4*)(dst + 0)  = *(ushort4*)&buf[0];
  *(ushort4*)(dst + 4)  = *(ushort4*)&buf[4];
  *(ushort4*)(dst + 8)  = *(ushort4*)&buf[8];
  *(ushort4*)(dst + 12) = *(ushort4*)&buf[12];
}

// ------- RMS norms; input = 16 split-K partials of ssm, row stride 512 ---------
__global__ __launch_bounds__(64) void rms_kernel(
    const float* __restrict__ part, u16* __restrict__ tsb,
    float* __restrict__ Bn, float* __restrict__ Cn)
{
  const int tok = blockIdx.x;
  const int lane = threadIdx.x;
  const size_t rowoff = (size_t)tok * 512;
  f32x4v t = (f32x4v){0.f, 0.f, 0.f, 0.f};
#pragma unroll
  for (int s = 0; s < 16; ++s)
    t += *(const f32x4v*)(part + (size_t)s * (BLT * 512) + rowoff + lane * 4);
  float ss = t[0]*t[0] + t[1]*t[1] + t[2]*t[2] + t[3]*t[3];
#pragma unroll
  for (int o = 32; o; o >>= 1) ss += __shfl_xor(ss, o);
  const float sc = rsqrtf(ss * (1.f / 256.f) + 1e-6f);
  ushort4 o4;
  o4.x = f2b(t[0] * sc); o4.y = f2b(t[1] * sc);
  o4.z = f2b(t[2] * sc); o4.w = f2b(t[3] * sc);
  *(ushort4*)(tsb + (size_t)tok * 256 + lane * 4) = o4;

  float v = 0.f;
  if (lane < 32) {
#pragma unroll
    for (int s = 0; s < 16; ++s)
      v += part[(size_t)s * (BLT * 512) + rowoff + 256 + lane];
  }
  float g = v * v;
#pragma unroll
  for (int o = 1; o < 16; o <<= 1) g += __shfl_xor(g, o);
  const float scBC = rsqrtf(g * (1.f / 16.f) + 1e-6f);
  if (lane < 16) Bn[(size_t)tok * 16 + lane] = v * scBC;
  else if (lane < 32) Cn[(size_t)tok * 16 + (lane - 16)] = v * scBC;
}

// ---------------- chunked scan phase 1: per-chunk partials (E, S) ----------------
__global__ __launch_bounds__(256) void scan_p1_kernel(
    const float* __restrict__ dtT, const u16* __restrict__ xT,
    const float* __restrict__ Bn, const float* __restrict__ A_log,
    float* __restrict__ partE, float* __restrict__ partS)
{
  __shared__ float Bsh[CL][16];
  const int tid = threadIdx.x;
  const int chunk = blockIdx.y;
  const int d = blockIdx.x * 64 + (tid >> 2);
  const int ln = tid & 3;
  const int tok0 = chunk * CL;
  {
    const int tt = tid >> 2, q = tid & 3;
    *(f32x4v*)&Bsh[tt][q * 4] = *(const f32x4v*)(Bn + (size_t)(tok0 + tt) * 16 + q * 4);
  }
  __syncthreads();
  float a[4];
#pragma unroll
  for (int j = 0; j < 4; ++j) a[j] = -__expf(A_log[(size_t)d * 16 + ln * 4 + j]);
  float E0 = 1.f, E1 = 1.f, E2 = 1.f, E3 = 1.f;
  float S0 = 0.f, S1 = 0.f, S2 = 0.f, S3 = 0.f;
  const float* dtp = dtT + (size_t)d * BLT + tok0;
  const u16* xp = xT + (size_t)d * BLT + tok0;
  for (int l = 0; l < CL; l += 4) {
    f32x4v dt4 = *(const f32x4v*)(dtp + l);
    ushort4 u4 = *(const ushort4*)(xp + l);
#pragma unroll
    for (int i = 0; i < 4; ++i) {
      const float dt = dt4[i];
      const float u = b2f(((const u16*)&u4)[i]);
      const float dtu = dt * u;
      f32x4v Bv = *(const f32x4v*)&Bsh[l + i][ln * 4];
      const float e0 = __expf(dt * a[0]);
      const float e1 = __expf(dt * a[1]);
      const float e2 = __expf(dt * a[2]);
      const float e3 = __expf(dt * a[3]);
      S0 = fmaf(S0, e0, dtu * Bv[0]); E0 *= e0;
      S1 = fmaf(S1, e1, dtu * Bv[1]); E1 *= e1;
      S2 = fmaf(S2, e2, dtu * Bv[2]); E2 *= e2;
      S3 = fmaf(S3, e3, dtu * Bv[3]); E3 *= e3;
    }
  }
  const size_t off = (size_t)chunk * (DIN * 16) + (size_t)d * 16 + ln * 4;
  f32x4v Ev = {E0, E1, E2, E3}, Sv = {S0, S1, S2, S3};
  *(f32x4v*)(partE + off) = Ev;
  *(f32x4v*)(partS + off) = Sv;
}

// ---------------- chunked scan phase 2: combine chunk partials ----------------
__global__ __launch_bounds__(256) void scan_p2_kernel(
    const float* __restrict__ partE, float* __restrict__ partS)
{
  const int dn = blockIdx.x * 256 + threadIdx.x;
  float s = 0.f;
  for (int c = 0; c < NCG; ++c) {
    if ((c & 15) == 0) s = 0.f;  // batch boundary reset
    const size_t off = (size_t)c * (DIN * 16) + dn;
    const float e = partE[off];
    const float ps = partS[off];
    partS[off] = s;
    s = fmaf(e, s, ps);
  }
}

// -------- chunked scan phase 3: re-scan, emit y; gate+yg staged in LDS ---------
__global__ __launch_bounds__(256) void scan_p3_kernel(
    const float* __restrict__ dtT, const u16* __restrict__ xT,
    const float* __restrict__ Bn, const float* __restrict__ Cn,
    const float* __restrict__ A_log, const float* __restrict__ Dv,
    const float* __restrict__ stateIn, const u16* __restrict__ proj,
    u16* __restrict__ yg)
{
  __shared__ float Bsh[CL][16], Csh[CL][16];
  __shared__ u16 gsh[CL][64], ysh[CL][64];
  const int tid = threadIdx.x;
  const int chunk = blockIdx.y;
  const int d0 = blockIdx.x * 64;
  const int dch = tid >> 2;             // 0..63
  const int d = d0 + dch;
  const int ln = tid & 3;
  const int tok0 = chunk * CL;
  {
    const int tt = tid >> 2, q = tid & 3;
    *(f32x4v*)&Bsh[tt][q * 4] = *(const f32x4v*)(Bn + (size_t)(tok0 + tt) * 16 + q * 4);
    *(f32x4v*)&Csh[tt][q * 4] = *(const f32x4v*)(Cn + (size_t)(tok0 + tt) * 16 + q * 4);
    const u16* grow = proj + (size_t)(tok0 + tt) * 16384 + DIN + d0 + q * 16;
#pragma unroll
    for (int qq = 0; qq < 4; ++qq)
      *(ushort4*)&gsh[tt][q * 16 + qq * 4] = *(const ushort4*)(grow + qq * 4);
  }
  __syncthreads();
  float a[4];
#pragma unroll
  for (int j = 0; j < 4; ++j) a[j] = -__expf(A_log[(size_t)d * 16 + ln * 4 + j]);
  f32x4v sv = *(const f32x4v*)(stateIn + (size_t)chunk * (DIN * 16) + (size_t)d * 16 + ln * 4);
  float S0 = sv[0], S1 = sv[1], S2 = sv[2], S3 = sv[3];
  const float Dd = Dv[d];
  const float* dtp = dtT + (size_t)d * BLT + tok0;
  const u16* xp = xT + (size_t)d * BLT + tok0;
  for (int l = 0; l < CL; l += 4) {
    f32x4v dt4 = *(const f32x4v*)(dtp + l);
    ushort4 u4 = *(const ushort4*)(xp + l);
#pragma unroll
    for (int i = 0; i < 4; ++i) {
      const float dt = dt4[i];
      const float u = b2f(((const u16*)&u4)[i]);
      const float dtu = dt * u;
      f32x4v Bv = *(const f32x4v*)&Bsh[l + i][ln * 4];
      f32x4v Cv = *(const f32x4v*)&Csh[l + i][ln * 4];
      const float e0 = __expf(dt * a[0]);
      const float e1 = __expf(dt * a[1]);
      const float e2 = __expf(dt * a[2]);
      const float e3 = __expf(dt * a[3]);
      float y;
      S0 = fmaf(S0, e0, dtu * Bv[0]); y = S0 * Cv[0];
      S1 = fmaf(S1, e1, dtu * Bv[1]); y = fmaf(S1, Cv[1], y);
      S2 = fmaf(S2, e2, dtu * Bv[2]); y = fmaf(S2, Cv[2], y);
      S3 = fmaf(S3, e3, dtu * Bv[3]); y = fmaf(S3, Cv[3], y);
      y += __shfl_xor(y, 1);
      y += __shfl_xor(y, 2);
      if (ln == 0) {
        const float yt = fmaf(u, Dd, y);
        const float gt = b2f(gsh[l + i][dch]);
        const float sg = gt / (1.f + __expf(-gt));
        ysh[l + i][dch] = f2b(yt * sg);
      }
    }
  }
  __syncthreads();
  {
    const int tt = tid >> 2, q = tid & 3;
    u16* yrow = yg + (size_t)(tok0 + tt) * DIN + d0 + q * 16;
#pragma unroll
    for (int qq = 0; qq < 4; ++qq)
      *(ushort4*)(yrow + qq * 4) = *(ushort4*)&ysh[tt][q * 16 + qq * 4];
  }
}

extern "C" void kernel_launch(void* const* d_in, const int* in_sizes, int n_in,
                              void* d_out, int out_size, void* d_ws, size_t ws_size,
                              hipStream_t stream) {
  const float* hs     = (const float*)d_in[0];
  const float* W_in   = (const float*)d_in[1];
  const float* conv_w = (const float*)d_in[2];
  const float* conv_b = (const float*)d_in[3];
  const float* W_x    = (const float*)d_in[4];
  const float* W_dt   = (const float*)d_in[5];
  const float* b_dt   = (const float*)d_in[6];
  const float* A_log  = (const float*)d_in[7];
  const float* Dv     = (const float*)d_in[8];
  const float* W_out  = (const float*)d_in[9];
  float* out = (float*)d_out;

  char* ws = (char*)d_ws;
  size_t off = 0;
  auto alloc = [&](size_t bytes) -> char* {
    char* p = ws + off;
    off += (bytes + 255) & ~(size_t)255;
    return p;
  };

  u16* W_in_b = (u16*)alloc(134217728);                // R1: W_in_bf16 -> ssm_part -> dt_T + W_out_b
  u16* hs_b = (u16*)alloc(16777216);                   // R2: hs_bf16 -> ts/Bn/Cn/W_dt
  u16* proj_b = (u16*)alloc((size_t)BLT * 16384 * 2);  // 67MB
  u16* x_b    = (u16*)alloc((size_t)BLT * DIN * 2);    // 33.5MB; after ssm: partE+partS
  u16* W_xp_b = (u16*)alloc((size_t)512 * DIN * 2);    // 8.4MB (padded to 512 rows)
  u16* yg_b   = (u16*)alloc((size_t)BLT * DIN * 2);    // 33.5MB
  u16* x_T    = (u16*)alloc((size_t)BLT * DIN * 2);    // 33.5MB [DIN][BLT]

  float* dt_T    = (float*)W_in_b;                     // [DIN][BLT] f32, 67MB
  float* ssm_part= (float*)W_in_b;                     // [16][2048][512] f32 = 67MB (pre-dt_T)
  u16*   W_out_b = (u16*)((char*)W_in_b + 67108864);
  u16*   ts_b    = (u16*)((char*)hs_b + 3145728);
  float* Bn      = (float*)((char*)hs_b + 3145728 + 1048576);
  float* Cn      = (float*)((char*)hs_b + 3145728 + 1048576 + 131072);
  u16*   W_dt_b  = (u16*)((char*)hs_b + 3145728 + 1048576 + 262144);
  float* partE   = (float*)x_b;
  float* partS   = (float*)((char*)x_b + 16777216);

  const int CG = 2048;
  // 1) convert GEMM1 operands (merged)
  cvt_in_kernel<<<CG, 256, 0, stream>>>(W_in, W_in_b, hs, hs_b);
  // 2) proj = hs @ W_in^T  (2048 x 16384, K=4096), bf16 out
  gemm256<1><<<dim3((16384 / 256) * (BLT / 256), 1), 512, 0, stream>>>(hs_b, W_in_b, proj_b, BLT, 16384, 4096, 4096);
  // 3) convert remaining weights (merged; W_x padded to 512 rows)
  cvt_weights_kernel<<<CG, 256, 0, stream>>>(W_out, W_out_b, W_dt, W_dt_b, W_x, W_xp_b);
  // 4) conv + silu -> x (bf16) AND x_T (fused transpose)
  conv_silu_tr_kernel<<<dim3(BLT / 64, DIN / 64), 256, 0, stream>>>(proj_b, conv_w, conv_b, x_b, x_T);
  // 5) ssm partials: x @ W_xp^T (N=512 padded, write cols<288), split-K=16
  gemm256<0><<<dim3((512 / 256) * (BLT / 256), 16), 512, 0, stream>>>(x_b, W_xp_b, ssm_part, BLT, 512, DIN, DIN / 16, nullptr, 288);
  // 6) rms norms (reduces the 16 partials; ts/B/C from cols 0..287)
  rms_kernel<<<BLT, 64, 0, stream>>>(ssm_part, ts_b, Bn, Cn);
  // 7) dt_T = softplus(W_dt @ ts^T + b_dt), f32 [DIN][BLT]
  gemm256<2><<<dim3((DIN / 256) * (BLT / 256), 1), 512, 0, stream>>>(W_dt_b, ts_b, dt_T, DIN, BLT, 256, 256, b_dt);
  // 8) chunked scan
  scan_p1_kernel<<<dim3(DIN / 64, NCG), 256, 0, stream>>>(dt_T, x_T, Bn, A_log, partE, partS);
  scan_p2_kernel<<<DIN * 16 / 256, 256, 0, stream>>>(partE, partS);
  scan_p3_kernel<<<dim3(DIN / 64, NCG), 256, 0, stream>>>(dt_T, x_T, Bn, Cn, A_log, Dv, partS, proj_b, yg_b);
  // 9) out = ygated @ W_out^T — 256x128 tiles, full K, direct f32 out (256 blocks)
  gemm256n128<<<(HH / 128) * (BLT / 256), 512, 0, stream>>>(yg_b, W_out_b, out, BLT, HH, DIN);
}

// Round 16
// 887.773 us; speedup vs baseline: 1.0188x; 1.0188x over previous
//
#include <hip/hip_runtime.h>
#include <hip/hip_bf16.h>

#define DIN 8192
#define HH 4096
#define BLT 2048   // total tokens (2*1024)
#define LSEQ 1024
#define CL 64      // scan chunk length
#define NCG 32     // total chunks (16 per batch)

typedef unsigned short u16;
typedef __bf16 bf16x8 __attribute__((ext_vector_type(8)));
typedef float f32x4v __attribute__((ext_vector_type(4)));

__device__ __forceinline__ u16 f2b(float f) {
  unsigned u = __float_as_uint(f);
  u += 0x7fff + ((u >> 16) & 1);
  return (u16)(u >> 16);
}
__device__ __forceinline__ float b2f(u16 h) {
  return __uint_as_float(((unsigned)h) << 16);
}

__device__ __forceinline__ void gl_lds16(const u16* g, u16* l) {
  __builtin_amdgcn_global_load_lds(
      (const __attribute__((address_space(1))) void*)g,
      (__attribute__((address_space(3))) void*)l, 16, 0, 0);
}

__device__ __forceinline__ int bsw(int r) { return (r & 3) ^ ((r >> 2) & 3); }

// ---- merged input converts: W_in (67.1M) + hs (8.4M), f32 -> bf16 ----
__global__ void cvt_in_kernel(const float* __restrict__ Win, u16* __restrict__ Winb,
                              const float* __restrict__ hs, u16* __restrict__ hsb) {
  const long stride = (long)gridDim.x * blockDim.x * 4;
  const long base = ((long)blockIdx.x * blockDim.x + threadIdx.x) * 4;
  for (long i = base; i < 67108864L; i += stride) {
    f32x4v v = *(const f32x4v*)(Win + i);
    ushort4 o;
    o.x = f2b(v[0]); o.y = f2b(v[1]); o.z = f2b(v[2]); o.w = f2b(v[3]);
    *(ushort4*)(Winb + i) = o;
  }
  for (long i = base; i < 8388608L; i += stride) {
    f32x4v v = *(const f32x4v*)(hs + i);
    ushort4 o;
    o.x = f2b(v[0]); o.y = f2b(v[1]); o.z = f2b(v[2]); o.w = f2b(v[3]);
    *(ushort4*)(hsb + i) = o;
  }
}

// ---- merged weight converts: W_out, W_dt, W_x (pad 288->512 rows) ----
__global__ void cvt_weights_kernel(
    const float* __restrict__ Wout, u16* __restrict__ Woutb,
    const float* __restrict__ Wdt, u16* __restrict__ Wdtb,
    const float* __restrict__ Wx, u16* __restrict__ Wxb)
{
  const long stride = (long)gridDim.x * blockDim.x * 4;
  const long base = ((long)blockIdx.x * blockDim.x + threadIdx.x) * 4;
  for (long i = base; i < 33554432L; i += stride) {
    f32x4v v = *(const f32x4v*)(Wout + i);
    ushort4 o;
    o.x = f2b(v[0]); o.y = f2b(v[1]); o.z = f2b(v[2]); o.w = f2b(v[3]);
    *(ushort4*)(Woutb + i) = o;
  }
  for (long i = base; i < 2097152L; i += stride) {
    f32x4v v = *(const f32x4v*)(Wdt + i);
    ushort4 o;
    o.x = f2b(v[0]); o.y = f2b(v[1]); o.z = f2b(v[2]); o.w = f2b(v[3]);
    *(ushort4*)(Wdtb + i) = o;
  }
  for (long i = base; i < (long)512 * DIN; i += stride) {
    ushort4 o;
    if (i < (long)288 * DIN) {
      f32x4v v = *(const f32x4v*)(Wx + i);
      o.x = f2b(v[0]); o.y = f2b(v[1]); o.z = f2b(v[2]); o.w = f2b(v[3]);
    } else {
      o.x = 0; o.y = 0; o.z = 0; o.w = 0;
    }
    *(ushort4*)(Wxb + i) = o;
  }
}

// ------- 256x256 8-wave GEMM, phase-split (reads-before-barrier), 3-stage -------
// Tile order: n-fastest (round-14 best).
// MODE 0: f32 out [z][M][N] partials (cols < nlim only).  MODE 1: bf16 out [M][N].
// MODE 2: f32 out [M][N] with fused softplus(acc + bias[row]) (dt path, A=W_dt).
template<int MODE>
__global__ __launch_bounds__(512, 2) void gemm256(
    const u16* __restrict__ A, const u16* __restrict__ B, void* __restrict__ Cp,
    int M, int N, int Kfull, int Ksub, const float* __restrict__ bias = nullptr,
    int nlim = 1 << 30)
{
  __shared__ __align__(16) u16 lds[3][2][8192];  // [buf][A=0/B=1][256 rows][32 k]
  const int tid = threadIdx.x;
  const int lane = tid & 63;
  const int wid = tid >> 6;
  const int wm = wid >> 2;
  const int wn = wid & 3;
  const int fr = lane & 15;
  const int fq = lane >> 4;
  const int fs = fq ^ bsw(fr);

  // XCD-aware swizzle over grid.x; n varies fastest
  const int nbx = N >> 8;
  const int cpx = gridDim.x >> 3;
  const int bid = blockIdx.x;
  const int swz = (bid & 7) * cpx + (bid >> 3);
  const long m0 = (long)(swz / nbx) << 8;
  const long n0 = (long)(swz % nbx) << 8;
  const long kbase = (long)blockIdx.y * Ksub;

  const int srow = tid >> 2;
  const int sseg = (tid & 3) ^ bsw(srow);
  const u16* ag0 = A + (m0 + srow) * (long)Kfull + kbase + sseg * 8;
  const u16* ag1 = ag0 + 128 * (long)Kfull;
  const u16* bg0 = B + (n0 + srow) * (long)Kfull + kbase + sseg * 8;
  const u16* bg1 = bg0 + 128 * (long)Kfull;

  auto stageA = [&](int c, int koff) {          // first halves of A and B tiles
    gl_lds16(ag0 + koff, &lds[c][0][tid * 8]);
    gl_lds16(bg0 + koff, &lds[c][1][tid * 8]);
  };
  auto stageB = [&](int c, int koff) {          // second halves
    gl_lds16(ag1 + koff, &lds[c][0][4096 + tid * 8]);
    gl_lds16(bg1 + koff, &lds[c][1][4096 + tid * 8]);
  };

  const int NT = Ksub >> 5;
  stageA(0, 0); stageB(0, 0);
  stageA(1, 32); stageB(1, 32);
  asm volatile("s_waitcnt vmcnt(4)" ::: "memory");  // tile0 landed
  __builtin_amdgcn_s_barrier();

  f32x4v acc[8][4];
#pragma unroll
  for (int i = 0; i < 8; ++i)
#pragma unroll
    for (int j = 0; j < 4; ++j) acc[i][j] = (f32x4v){0.f, 0.f, 0.f, 0.f};

  const int aoff = (wm * 128 + fr) * 32 + fs * 8;
  const int boff = (wn * 64 + fr) * 32 + fs * 8;
  bf16x8 af[4], bfg[4], al[4];

  int c = 0, cs = 2;
  for (int t = 0; t < NT; ++t) {
    const u16* Asl = &lds[c][0][0];
    const u16* Bsl = &lds[c][1][0];
    const bool pf = (t + 2 < NT);
    // ---- phase A: issue reads (af,bfg), issue half of stage(t+2), barrier ----
#pragma unroll
    for (int mi = 0; mi < 4; ++mi) af[mi] = *(const bf16x8*)(Asl + aoff + mi * 512);
#pragma unroll
    for (int ni = 0; ni < 4; ++ni) bfg[ni] = *(const bf16x8*)(Bsl + boff + ni * 512);
    if (pf) stageA(cs, (t + 2) * 32);
    __builtin_amdgcn_s_barrier();                       // ds latency hides here
    asm volatile("s_waitcnt lgkmcnt(0)" ::: "memory");
    __builtin_amdgcn_sched_barrier(0);
    __builtin_amdgcn_s_setprio(1);
#pragma unroll
    for (int mi = 0; mi < 4; ++mi)
#pragma unroll
      for (int ni = 0; ni < 4; ++ni)
        acc[mi][ni] = __builtin_amdgcn_mfma_f32_16x16x32_bf16(af[mi], bfg[ni], acc[mi][ni], 0, 0, 0);
    __builtin_amdgcn_s_setprio(0);
    // ---- phase B: issue reads (al), other half of stage(t+2), barrier ----
#pragma unroll
    for (int mi = 0; mi < 4; ++mi) al[mi] = *(const bf16x8*)(Asl + aoff + 2048 + mi * 512);
    if (pf) stageB(cs, (t + 2) * 32);
    __builtin_amdgcn_s_barrier();
    asm volatile("s_waitcnt lgkmcnt(0)" ::: "memory");
    __builtin_amdgcn_sched_barrier(0);
    __builtin_amdgcn_s_setprio(1);
#pragma unroll
    for (int mi = 0; mi < 4; ++mi)
#pragma unroll
      for (int ni = 0; ni < 4; ++ni)
        acc[mi + 4][ni] = __builtin_amdgcn_mfma_f32_16x16x32_bf16(al[mi], bfg[ni], acc[mi + 4][ni], 0, 0, 0);
    __builtin_amdgcn_s_setprio(0);
    if (pf) {
      asm volatile("s_waitcnt vmcnt(4)" ::: "memory");  // t+1 landed; t+2 in flight
    } else {
      asm volatile("s_waitcnt vmcnt(0)" ::: "memory");  // drain tail
    }
    __builtin_amdgcn_s_barrier();   // all waves: buf c reads done + t+1 visible
    c = (c == 2) ? 0 : c + 1;
    cs = (cs == 2) ? 0 : cs + 1;
  }

  float* Cf = (float*)Cp + (size_t)blockIdx.y * M * N;
#pragma unroll
  for (int mi = 0; mi < 8; ++mi) {
#pragma unroll
    for (int ni = 0; ni < 4; ++ni) {
      const long col = n0 + wn * 64 + ni * 16 + fr;
      const long rbase = m0 + wm * 128 + mi * 16 + fq * 4;
#pragma unroll
      for (int r = 0; r < 4; ++r) {
        if constexpr (MODE == 1) {
          ((u16*)Cp)[(rbase + r) * N + col] = f2b(acc[mi][ni][r]);
        } else if constexpr (MODE == 0) {
          if (col < nlim) Cf[(rbase + r) * N + col] = acc[mi][ni][r];
        } else {
          const float z = acc[mi][ni][r] + bias[rbase + r];
          ((float*)Cp)[(rbase + r) * N + col] = (z > 20.f) ? z : log1pf(__expf(z));
        }
      }
    }
  }
}

// ---- 256x128-tile 8-wave GEMM (full K, f32 direct out) — for out = yg @ W_out^T ----
// 8 waves as 4(m) x 2(n), per-wave 64x64 output. LDS 3 x (16KB A + 8KB B) = 72KB.
// n-fastest tile order (round-14 best).
__global__ __launch_bounds__(512, 2) void gemm256n128(
    const u16* __restrict__ A, const u16* __restrict__ B, float* __restrict__ Cp,
    int M, int N, int K)
{
  __shared__ __align__(16) u16 lds[3][12288];   // [buf][A: 0..8191 | B: 8192..12287]
  const int tid = threadIdx.x;
  const int lane = tid & 63;
  const int wid = tid >> 6;
  const int wm = wid >> 1;    // 0..3
  const int wn = wid & 1;     // 0..1
  const int fr = lane & 15;
  const int fq = lane >> 4;
  const int fs = fq ^ bsw(fr);

  // XCD-aware swizzle; n varies fastest
  const int nbx = N >> 7;
  const int cpx = gridDim.x >> 3;
  const int bid = blockIdx.x;
  const int swz = (bid & 7) * cpx + (bid >> 3);
  const long m0 = (long)(swz / nbx) << 8;
  const long n0 = (long)(swz % nbx) << 7;

  const int srow = tid >> 2;                    // 0..127
  const int sseg = (tid & 3) ^ bsw(srow);
  const u16* ag0 = A + (m0 + srow) * (long)K + sseg * 8;
  const u16* ag1 = ag0 + 128 * (long)K;
  const u16* bg0 = B + (n0 + srow) * (long)K + sseg * 8;

  auto stage = [&](int c, int koff) {
    gl_lds16(ag0 + koff, &lds[c][tid * 8]);
    gl_lds16(ag1 + koff, &lds[c][4096 + tid * 8]);
    gl_lds16(bg0 + koff, &lds[c][8192 + tid * 8]);
  };

  const int NT = K >> 5;
  stage(0, 0);
  stage(1, 32);
  asm volatile("s_waitcnt vmcnt(3)" ::: "memory");   // tile0's 3 loads landed
  __builtin_amdgcn_s_barrier();

  f32x4v acc[4][4];
#pragma unroll
  for (int i = 0; i < 4; ++i)
#pragma unroll
    for (int j = 0; j < 4; ++j) acc[i][j] = (f32x4v){0.f, 0.f, 0.f, 0.f};

  const int aoff = (wm * 64 + fr) * 32 + fs * 8;     // + mi*512
  const int boff = 8192 + (wn * 64 + fr) * 32 + fs * 8;  // + ni*512
  bf16x8 af[4], bfg[4];

  int c = 0, cs = 2;
  for (int t = 0; t < NT; ++t) {
    const u16* L = &lds[c][0];
    const bool pf = (t + 2 < NT);
#pragma unroll
    for (int mi = 0; mi < 4; ++mi) af[mi] = *(const bf16x8*)(L + aoff + mi * 512);
#pragma unroll
    for (int ni = 0; ni < 4; ++ni) bfg[ni] = *(const bf16x8*)(L + boff + ni * 512);
    if (pf) stage(cs, (t + 2) * 32);
    __builtin_amdgcn_s_barrier();
    asm volatile("s_waitcnt lgkmcnt(0)" ::: "memory");
    __builtin_amdgcn_sched_barrier(0);
    __builtin_amdgcn_s_setprio(1);
#pragma unroll
    for (int mi = 0; mi < 4; ++mi)
#pragma unroll
      for (int ni = 0; ni < 4; ++ni)
        acc[mi][ni] = __builtin_amdgcn_mfma_f32_16x16x32_bf16(af[mi], bfg[ni], acc[mi][ni], 0, 0, 0);
    __builtin_amdgcn_s_setprio(0);
    if (pf) {
      asm volatile("s_waitcnt vmcnt(3)" ::: "memory");  // t+1 landed; t+2 in flight
    } else {
      asm volatile("s_waitcnt vmcnt(0)" ::: "memory");  // drain tail
    }
    __builtin_amdgcn_s_barrier();   // reads of buf c done + t+1 visible
    c = (c == 2) ? 0 : c + 1;
    cs = (cs == 2) ? 0 : cs + 1;
  }

#pragma unroll
  for (int mi = 0; mi < 4; ++mi) {
#pragma unroll
    for (int ni = 0; ni < 4; ++ni) {
      const long col = n0 + wn * 64 + ni * 16 + fr;
      const long rbase = m0 + wm * 64 + mi * 16 + fq * 4;
#pragma unroll
      for (int r = 0; r < 4; ++r)
        Cp[(rbase + r) * N + col] = acc[mi][ni][r];
    }
  }
}

// ---- causal conv (K=4) + SiLU, 64x64 tile; writes x AND x^T (LDS transpose) ----
__global__ __launch_bounds__(256) void conv_silu_tr_kernel(
    const u16* __restrict__ proj, const float* __restrict__ conv_w,
    const float* __restrict__ conv_b, u16* __restrict__ xb, u16* __restrict__ xT)
{
  __shared__ u16 xt[64][68];   // +4 pad keeps 8B align, breaks bank conflicts
  const int t = threadIdx.x;
  const int tr = t >> 4;          // 0..15 token row base
  const int dqi = t & 15;         // d offset = dqi*4
  const long tok0 = (long)blockIdx.x * 64;
  const int d0 = blockIdx.y * 64;
  const int d = d0 + dqi * 4;
  f32x4v cb = *(const f32x4v*)(conv_b + d);
  f32x4v w0 = *(const f32x4v*)(conv_w + (size_t)(d + 0) * 4);
  f32x4v w1 = *(const f32x4v*)(conv_w + (size_t)(d + 1) * 4);
  f32x4v w2 = *(const f32x4v*)(conv_w + (size_t)(d + 2) * 4);
  f32x4v w3 = *(const f32x4v*)(conv_w + (size_t)(d + 3) * 4);
#pragma unroll
  for (int tt = 0; tt < 4; ++tt) {
    const long tok = tok0 + tr + tt * 16;
    const int l = (int)(tok & (LSEQ - 1));
    float a0 = cb[0], a1 = cb[1], a2 = cb[2], a3 = cb[3];
#pragma unroll
    for (int j = 0; j < 4; ++j) {
      const int lj = l - 3 + j;
      if (lj >= 0) {
        ushort4 xv = *(const ushort4*)(proj + (tok - 3 + j) * 16384 + d);
        a0 = fmaf(w0[j], b2f(xv.x), a0);
        a1 = fmaf(w1[j], b2f(xv.y), a1);
        a2 = fmaf(w2[j], b2f(xv.z), a2);
        a3 = fmaf(w3[j], b2f(xv.w), a3);
      }
    }
    ushort4 o;
    o.x = f2b(a0 / (1.f + __expf(-a0)));
    o.y = f2b(a1 / (1.f + __expf(-a1)));
    o.z = f2b(a2 / (1.f + __expf(-a2)));
    o.w = f2b(a3 / (1.f + __expf(-a3)));
    *(ushort4*)(xb + tok * DIN + d) = o;
    *(ushort4*)(&xt[tr + tt * 16][dqi * 4]) = o;
  }
  __syncthreads();
  // transpose out: thread t -> d_local = t>>2, token quarter = t&3
  const int dl = t >> 2;
  const int tq = t & 3;
  u16 buf[16];
#pragma unroll
  for (int i = 0; i < 16; ++i) buf[i] = xt[tq * 16 + i][dl];
  u16* dst = xT + (size_t)(d0 + dl) * BLT + tok0 + tq * 16;
  *(ushort4*)(dst + 0)  = *(ushort4*)&buf[0];
  *(ushort4*)(dst + 4)  = *(ushort4*)&buf[4];
  *(ushort4*)(dst + 8)  = *(ushort4*)&buf[8];
  *(ushort4*)(dst + 12) = *(ushort4*)&buf[12];
}

// ------- RMS norms; input = 16 split-K partials of ssm, row stride 512 ---------
__global__ __launch_bounds__(64) void rms_kernel(
    const float* __restrict__ part, u16* __restrict__ tsb,
    float* __restrict__ Bn, float* __restrict__ Cn)
{
  const int tok = blockIdx.x;
  const int lane = threadIdx.x;
  const size_t rowoff = (size_t)tok * 512;
  f32x4v t = (f32x4v){0.f, 0.f, 0.f, 0.f};
#pragma unroll
  for (int s = 0; s < 16; ++s)
    t += *(const f32x4v*)(part + (size_t)s * (BLT * 512) + rowoff + lane * 4);
  float ss = t[0]*t[0] + t[1]*t[1] + t[2]*t[2] + t[3]*t[3];
#pragma unroll
  for (int o = 32; o; o >>= 1) ss += __shfl_xor(ss, o);
  const float sc = rsqrtf(ss * (1.f / 256.f) + 1e-6f);
  ushort4 o4;
  o4.x = f2b(t[0] * sc); o4.y = f2b(t[1] * sc);
  o4.z = f2b(t[2] * sc); o4.w = f2b(t[3] * sc);
  *(ushort4*)(tsb + (size_t)tok * 256 + lane * 4) = o4;

  float v = 0.f;
  if (lane < 32) {
#pragma unroll
    for (int s = 0; s < 16; ++s)
      v += part[(size_t)s * (BLT * 512) + rowoff + 256 + lane];
  }
  float g = v * v;
#pragma unroll
  for (int o = 1; o < 16; o <<= 1) g += __shfl_xor(g, o);
  const float scBC = rsqrtf(g * (1.f / 16.f) + 1e-6f);
  if (lane < 16) Bn[(size_t)tok * 16 + lane] = v * scBC;
  else if (lane < 32) Cn[(size_t)tok * 16 + (lane - 16)] = v * scBC;
}

// ---------------- chunked scan phase 1: per-chunk partials (E, S) ----------------
__global__ __launch_bounds__(256) void scan_p1_kernel(
    const float* __restrict__ dtT, const u16* __restrict__ xT,
    const float* __restrict__ Bn, const float* __restrict__ A_log,
    float* __restrict__ partE, float* __restrict__ partS)
{
  __shared__ float Bsh[CL][16];
  const int tid = threadIdx.x;
  const int chunk = blockIdx.y;
  const int d = blockIdx.x * 64 + (tid >> 2);
  const int ln = tid & 3;
  const int tok0 = chunk * CL;
  {
    const int tt = tid >> 2, q = tid & 3;
    *(f32x4v*)&Bsh[tt][q * 4] = *(const f32x4v*)(Bn + (size_t)(tok0 + tt) * 16 + q * 4);
  }
  __syncthreads();
  float a[4];
#pragma unroll
  for (int j = 0; j < 4; ++j) a[j] = -__expf(A_log[(size_t)d * 16 + ln * 4 + j]);
  float E0 = 1.f, E1 = 1.f, E2 = 1.f, E3 = 1.f;
  float S0 = 0.f, S1 = 0.f, S2 = 0.f, S3 = 0.f;
  const float* dtp = dtT + (size_t)d * BLT + tok0;
  const u16* xp = xT + (size_t)d * BLT + tok0;
  for (int l = 0; l < CL; l += 4) {
    f32x4v dt4 = *(const f32x4v*)(dtp + l);
    ushort4 u4 = *(const ushort4*)(xp + l);
#pragma unroll
    for (int i = 0; i < 4; ++i) {
      const float dt = dt4[i];
      const float u = b2f(((const u16*)&u4)[i]);
      const float dtu = dt * u;
      f32x4v Bv = *(const f32x4v*)&Bsh[l + i][ln * 4];
      const float e0 = __expf(dt * a[0]);
      const float e1 = __expf(dt * a[1]);
      const float e2 = __expf(dt * a[2]);
      const float e3 = __expf(dt * a[3]);
      S0 = fmaf(S0, e0, dtu * Bv[0]); E0 *= e0;
      S1 = fmaf(S1, e1, dtu * Bv[1]); E1 *= e1;
      S2 = fmaf(S2, e2, dtu * Bv[2]); E2 *= e2;
      S3 = fmaf(S3, e3, dtu * Bv[3]); E3 *= e3;
    }
  }
  const size_t off = (size_t)chunk * (DIN * 16) + (size_t)d * 16 + ln * 4;
  f32x4v Ev = {E0, E1, E2, E3}, Sv = {S0, S1, S2, S3};
  *(f32x4v*)(partE + off) = Ev;
  *(f32x4v*)(partS + off) = Sv;
}

// ---------------- chunked scan phase 2: combine chunk partials ----------------
__global__ __launch_bounds__(256) void scan_p2_kernel(
    const float* __restrict__ partE, float* __restrict__ partS)
{
  const int dn = blockIdx.x * 256 + threadIdx.x;
  float s = 0.f;
  for (int c = 0; c < NCG; ++c) {
    if ((c & 15) == 0) s = 0.f;  // batch boundary reset
    const size_t off = (size_t)c * (DIN * 16) + dn;
    const float e = partE[off];
    const float ps = partS[off];
    partS[off] = s;
    s = fmaf(e, s, ps);
  }
}

// -------- chunked scan phase 3: re-scan, emit y; gate+yg staged in LDS ---------
__global__ __launch_bounds__(256) void scan_p3_kernel(
    const float* __restrict__ dtT, const u16* __restrict__ xT,
    const float* __restrict__ Bn, const float* __restrict__ Cn,
    const float* __restrict__ A_log, const float* __restrict__ Dv,
    const float* __restrict__ stateIn, const u16* __restrict__ proj,
    u16* __restrict__ yg)
{
  __shared__ float Bsh[CL][16], Csh[CL][16];
  __shared__ u16 gsh[CL][64], ysh[CL][64];
  const int tid = threadIdx.x;
  const int chunk = blockIdx.y;
  const int d0 = blockIdx.x * 64;
  const int dch = tid >> 2;             // 0..63
  const int d = d0 + dch;
  const int ln = tid & 3;
  const int tok0 = chunk * CL;
  {
    const int tt = tid >> 2, q = tid & 3;
    *(f32x4v*)&Bsh[tt][q * 4] = *(const f32x4v*)(Bn + (size_t)(tok0 + tt) * 16 + q * 4);
    *(f32x4v*)&Csh[tt][q * 4] = *(const f32x4v*)(Cn + (size_t)(tok0 + tt) * 16 + q * 4);
    const u16* grow = proj + (size_t)(tok0 + tt) * 16384 + DIN + d0 + q * 16;
#pragma unroll
    for (int qq = 0; qq < 4; ++qq)
      *(ushort4*)&gsh[tt][q * 16 + qq * 4] = *(const ushort4*)(grow + qq * 4);
  }
  __syncthreads();
  float a[4];
#pragma unroll
  for (int j = 0; j < 4; ++j) a[j] = -__expf(A_log[(size_t)d * 16 + ln * 4 + j]);
  f32x4v sv = *(const f32x4v*)(stateIn + (size_t)chunk * (DIN * 16) + (size_t)d * 16 + ln * 4);
  float S0 = sv[0], S1 = sv[1], S2 = sv[2], S3 = sv[3];
  const float Dd = Dv[d];
  const float* dtp = dtT + (size_t)d * BLT + tok0;
  const u16* xp = xT + (size_t)d * BLT + tok0;
  for (int l = 0; l < CL; l += 4) {
    f32x4v dt4 = *(const f32x4v*)(dtp + l);
    ushort4 u4 = *(const ushort4*)(xp + l);
#pragma unroll
    for (int i = 0; i < 4; ++i) {
      const float dt = dt4[i];
      const float u = b2f(((const u16*)&u4)[i]);
      const float dtu = dt * u;
      f32x4v Bv = *(const f32x4v*)&Bsh[l + i][ln * 4];
      f32x4v Cv = *(const f32x4v*)&Csh[l + i][ln * 4];
      const float e0 = __expf(dt * a[0]);
      const float e1 = __expf(dt * a[1]);
      const float e2 = __expf(dt * a[2]);
      const float e3 = __expf(dt * a[3]);
      float y;
      S0 = fmaf(S0, e0, dtu * Bv[0]); y = S0 * Cv[0];
      S1 = fmaf(S1, e1, dtu * Bv[1]); y = fmaf(S1, Cv[1], y);
      S2 = fmaf(S2, e2, dtu * Bv[2]); y = fmaf(S2, Cv[2], y);
      S3 = fmaf(S3, e3, dtu * Bv[3]); y = fmaf(S3, Cv[3], y);
      y += __shfl_xor(y, 1);
      y += __shfl_xor(y, 2);
      if (ln == 0) {
        const float yt = fmaf(u, Dd, y);
        const float gt = b2f(gsh[l + i][dch]);
        const float sg = gt / (1.f + __expf(-gt));
        ysh[l + i][dch] = f2b(yt * sg);
      }
    }
  }
  __syncthreads();
  {
    const int tt = tid >> 2, q = tid & 3;
    u16* yrow = yg + (size_t)(tok0 + tt) * DIN + d0 + q * 16;
#pragma unroll
    for (int qq = 0; qq < 4; ++qq)
      *(ushort4*)(yrow + qq * 4) = *(ushort4*)&ysh[tt][q * 16 + qq * 4];
  }
}

extern "C" void kernel_launch(void* const* d_in, const int* in_sizes, int n_in,
                              void* d_out, int out_size, void* d_ws, size_t ws_size,
                              hipStream_t stream) {
  const float* hs     = (const float*)d_in[0];
  const float* W_in   = (const float*)d_in[1];
  const float* conv_w = (const float*)d_in[2];
  const float* conv_b = (const float*)d_in[3];
  const float* W_x    = (const float*)d_in[4];
  const float* W_dt   = (const float*)d_in[5];
  const float* b_dt   = (const float*)d_in[6];
  const float* A_log  = (const float*)d_in[7];
  const float* Dv     = (const float*)d_in[8];
  const float* W_out  = (const float*)d_in[9];
  float* out = (float*)d_out;

  char* ws = (char*)d_ws;
  size_t off = 0;
  auto alloc = [&](size_t bytes) -> char* {
    char* p = ws + off;
    off += (bytes + 255) & ~(size_t)255;
    return p;
  };

  u16* W_in_b = (u16*)alloc(134217728);                // R1: W_in_bf16 -> ssm_part -> dt_T + W_out_b
  u16* hs_b = (u16*)alloc(16777216);                   // R2: hs_bf16 -> ts/Bn/Cn/W_dt
  u16* proj_b = (u16*)alloc((size_t)BLT * 16384 * 2);  // 67MB
  u16* x_b    = (u16*)alloc((size_t)BLT * DIN * 2);    // 33.5MB; after ssm: partE+partS
  u16* W_xp_b = (u16*)alloc((size_t)512 * DIN * 2);    // 8.4MB (padded to 512 rows)
  u16* yg_b   = (u16*)alloc((size_t)BLT * DIN * 2);    // 33.5MB
  u16* x_T    = (u16*)alloc((size_t)BLT * DIN * 2);    // 33.5MB [DIN][BLT]

  float* dt_T    = (float*)W_in_b;                     // [DIN][BLT] f32, 67MB
  float* ssm_part= (float*)W_in_b;                     // [16][2048][512] f32 = 67MB (pre-dt_T)
  u16*   W_out_b = (u16*)((char*)W_in_b + 67108864);
  u16*   ts_b    = (u16*)((char*)hs_b + 3145728);
  float* Bn      = (float*)((char*)hs_b + 3145728 + 1048576);
  float* Cn      = (float*)((char*)hs_b + 3145728 + 1048576 + 131072);
  u16*   W_dt_b  = (u16*)((char*)hs_b + 3145728 + 1048576 + 262144);
  float* partE   = (float*)x_b;
  float* partS   = (float*)((char*)x_b + 16777216);

  const int CG = 2048;
  // 1) convert GEMM1 operands (merged)
  cvt_in_kernel<<<CG, 256, 0, stream>>>(W_in, W_in_b, hs, hs_b);
  // 2) proj = hs @ W_in^T  (2048 x 16384, K=4096), bf16 out
  gemm256<1><<<dim3((16384 / 256) * (BLT / 256), 1), 512, 0, stream>>>(hs_b, W_in_b, proj_b, BLT, 16384, 4096, 4096);
  // 3) convert remaining weights (merged; W_x padded to 512 rows)
  cvt_weights_kernel<<<CG, 256, 0, stream>>>(W_out, W_out_b, W_dt, W_dt_b, W_x, W_xp_b);
  // 4) conv + silu -> x (bf16) AND x_T (fused transpose)
  conv_silu_tr_kernel<<<dim3(BLT / 64, DIN / 64), 256, 0, stream>>>(proj_b, conv_w, conv_b, x_b, x_T);
  // 5) ssm partials: x @ W_xp^T (N=512 padded, write cols<288), split-K=16
  gemm256<0><<<dim3((512 / 256) * (BLT / 256), 16), 512, 0, stream>>>(x_b, W_xp_b, ssm_part, BLT, 512, DIN, DIN / 16, nullptr, 288);
  // 6) rms norms (reduces the 16 partials; ts/B/C from cols 0..287)
  rms_kernel<<<BLT, 64, 0, stream>>>(ssm_part, ts_b, Bn, Cn);
  // 7) dt_T = softplus(W_dt @ ts^T + b_dt), f32 [DIN][BLT]
  gemm256<2><<<dim3((DIN / 256) * (BLT / 256), 1), 512, 0, stream>>>(W_dt_b, ts_b, dt_T, DIN, BLT, 256, 256, b_dt);
  // 8) chunked scan
  scan_p1_kernel<<<dim3(DIN / 64, NCG), 256, 0, stream>>>(dt_T, x_T, Bn, A_log, partE, partS);
  scan_p2_kernel<<<DIN * 16 / 256, 256, 0, stream>>>(partE, partS);
  scan_p3_kernel<<<dim3(DIN / 64, NCG), 256, 0, stream>>>(dt_T, x_T, Bn, Cn, A_log, Dv, partS, proj_b, yg_b);
  // 9) out = ygated @ W_out^T — 256x128 tiles, full K, direct f32 out (256 blocks)
  gemm256n128<<<(HH / 128) * (BLT / 256), 512, 0, stream>>>(yg_b, W_out_b, out, BLT, HH, DIN);
}